// Round 12
// baseline (135.332 us; speedup 1.0000x reference)
//
#include <hip/hip_runtime.h>
#include <hip/hip_bf16.h>

#define D 96
#define CAP 32          // per-node neighbor capacity; deg>32 -> LDS overflow list
#define NB1 512         // scatter blocks (E/512 = 1563 edges each; R22: was 256)
#define BUKSHIFT 5      // bucket = dst >> 5 : 32 nodes per bucket (R22: revert to R10)
#define BUKN 32
#define CAPB 1024       // bucket edge capacity (mean ~512, +22 sigma)
#define NBUK_MAX 2048
#define KMAX 7          // ceil(nbuk/256): nbuk=1563 -> 7 strides of 256
#define OVL_MAX 256     // per-bucket LDS overflow (expected total ~2-5 edges)
#define CSMAX 1568      // staged-edge LDS capacity (CS = 1563)

typedef __attribute__((ext_vector_type(8))) short bf16x8;
typedef __attribute__((ext_vector_type(4))) float f32x4;
typedef __attribute__((ext_vector_type(4))) short s16x4;
typedef unsigned u32x3 __attribute__((ext_vector_type(3), aligned(4)));

__device__ __forceinline__ short f2bf(float f)
{
    union { __hip_bfloat16 h; short s; } u;
    u.h = __float2bfloat16(f);
    return u.s;
}

__device__ __forceinline__ bf16x8 load_frag(const float* p)
{
    float4 lo = *(const float4*)p;
    float4 hi = *(const float4*)(p + 4);
    bf16x8 r;
    r[0] = f2bf(lo.x); r[1] = f2bf(lo.y); r[2] = f2bf(lo.z); r[3] = f2bf(lo.w);
    r[4] = f2bf(hi.x); r[5] = f2bf(hi.y); r[6] = f2bf(hi.z); r[7] = f2bf(hi.w);
    return r;
}

__device__ __forceinline__ float bf_lo(unsigned p) { return __uint_as_float(p << 16); }
__device__ __forceinline__ float bf_hi(unsigned p) { return __uint_as_float(p & 0xFFFF0000u); }

// ---------------------------------------------------------------------------
// K0: init — fragment-ordered bf16 W table wbf[36][64] (36 KB) + zero bcnt.
// ---------------------------------------------------------------------------
__global__ __launch_bounds__(256) void init_kernel(
    const float* __restrict__ Wl, const float* __restrict__ Wr,
    __hip_bfloat16* __restrict__ wbf, int* __restrict__ bcnt, int nbuk)
{
    const int idx = blockIdx.x * 256 + threadIdx.x;
    if (idx < nbuk) bcnt[idx] = 0;
    if (idx < 2304) {
        int mat = idx / 1152;                    // 0=Wl, 1=Wr
        int rem = idx - mat * 1152;
        int n  = rem / 12;                       // W row = output col (0..95)
        int k8 = rem - n * 12;                   // 8-float group along K
        const float* Wp = mat ? Wr : Wl;
        bf16x8 v = load_frag(Wp + (size_t)n * D + k8 * 8);
        int ct = n >> 4, m = n & 15, kt = k8 >> 2, quad = k8 & 3;
        ((bf16x8*)wbf)[(mat * 18 + ct * 3 + kt) * 64 + quad * 16 + m] = v;
    }
}

// ---------------------------------------------------------------------------
// K1 (fused): bid<NB1 -> LDS-staged self-reserving scatter (R20/R18).
// R22: NB1=512 — scatter was the kernel tail at 1 block/CU x 4 waves; halving
// per-block work and doubling scatter-wave TLP shortens the serial passes.
// bid>=NB1 -> gemm. R22 epilogue: SWAPPED-operand MFMA (mfma(w,x) — A/B lane
// layouts are symmetric, C/D col=lane&15 becomes the NODE) so each lane's 4
// acc regs = 4 consecutive cols of one node -> one 8-B bf16x4 hl store + one
// 16-B float4 hrs store per ct (48 scalar stores/thread -> 12 vector).
// 4-aligned col blocks never straddle the 24-col slice boundary (24%4==0).
// ---------------------------------------------------------------------------
__global__ __launch_bounds__(256) void p2_gemm(
    const int* __restrict__ src, const int* __restrict__ dst,
    int* __restrict__ bcnt, unsigned* __restrict__ ebuf,
    const float* __restrict__ x, const __hip_bfloat16* __restrict__ wbf,
    __hip_bfloat16* __restrict__ hl, float* __restrict__ hrs,
    int nbuk, int N, int E)
{
    if (blockIdx.x < NB1) {
        __shared__ int mo[NBUK_MAX];             // 6.2 KB used
        __shared__ unsigned stg[CSMAX];          // 6.3 KB staged packed edges
        const int t = threadIdx.x;
        for (int i = t; i < nbuk; i += 256) mo[i] = 0;
        __syncthreads();
        const int CS = (E + NB1 - 1) / NB1;      // 1563
        const int base = blockIdx.x * CS;
        int lim = E - base; if (lim > CS) lim = CS; if (lim < 0) lim = 0;
        // pass 1: count + stage (dst/src loads pipelined by unroll)
        #pragma unroll 4
        for (int i = t; i < lim; i += 256) {
            int e = base + i;
            int d = dst[e], s = src[e];
            int bu = d >> BUKSHIFT;
            atomicAdd(&mo[bu], 1);
            stg[i] = (unsigned)s | ((unsigned)(d & (BUKN - 1)) << 16)
                                 | ((unsigned)bu << 21);
        }
        __syncthreads();
        // pass 2: aggregated global reservation, back-to-back atomics
        int c7[KMAX], b7[KMAX];
        #pragma unroll
        for (int k = 0; k < KMAX; ++k) {
            int i = t + k * 256;
            c7[k] = (i < nbuk) ? mo[i] : 0;
        }
        #pragma unroll
        for (int k = 0; k < KMAX; ++k) {
            int i = t + k * 256;
            b7[k] = (i < nbuk) ? atomicAdd(&bcnt[i], c7[k]) : 0;
        }
        #pragma unroll
        for (int k = 0; k < KMAX; ++k) {
            int i = t + k * 256;
            if (i < nbuk) mo[i] = i * CAPB + b7[k];
        }
        __syncthreads();
        // pass 3: place edges — no global reads, stores fire-and-forget
        #pragma unroll 4
        for (int i = t; i < lim; i += 256) {
            unsigned u = stg[i];
            int bu = (int)(u >> 21);
            int g = atomicAdd(&mo[bu], 1);       // LDS atomic
            if (g < (bu + 1) * CAPB)             // capacity guard (astronomic)
                ebuf[g] = u & 0x1FFFFFu;         // src | dl<<16
        }
        return;
    }

    // ---- gemm role (wbf table verified R13; swapped-op layout derived from
    //      verified-R4 mapping by A/B fragment symmetry) ----
    const int gk = blockIdx.x - NB1;
    const int gwave = (gk * 256 + threadIdx.x) >> 6;
    const int nrt = N / 16;                      // 3125 (exact)
    if (gwave >= nrt) return;
    const int lane = threadIdx.x & 63;
    const int m = lane & 15, quad = lane >> 4;
    const int row = gwave * 16 + m;
    const int node = row;                        // with swapped ops, col=node=m
    const bf16x8* wb = (const bf16x8*)wbf;

    bf16x8 a[3];
    #pragma unroll
    for (int kt = 0; kt < 3; ++kt)
        a[kt] = load_frag(x + (size_t)row * D + kt * 32 + quad * 8);

    #pragma unroll
    for (int ct = 0; ct < 6; ++ct) {
        f32x4 accl = {0.f, 0.f, 0.f, 0.f};
        f32x4 accr = {0.f, 0.f, 0.f, 0.f};
        #pragma unroll
        for (int kt = 0; kt < 3; ++kt)
            accl = __builtin_amdgcn_mfma_f32_16x16x32_bf16(
                wb[(ct * 3 + kt) * 64 + lane], a[kt], accl, 0, 0, 0);
        #pragma unroll
        for (int kt = 0; kt < 3; ++kt)
            accr = __builtin_amdgcn_mfma_f32_16x16x32_bf16(
                wb[(18 + ct * 3 + kt) * 64 + lane], a[kt], accr, 0, 0, 0);
        // lane holds D[row=quad*4+reg][col=m]: 4 consecutive output cols of
        // 'node' at colb = ct*16 + quad*4 (never straddles a 24-boundary)
        int colb = ct * 16 + quad * 4;
        int sl = colb / 24, c = colb - sl * 24;
        s16x4 hv;
        hv[0] = f2bf(accl[0]); hv[1] = f2bf(accl[1]);
        hv[2] = f2bf(accl[2]); hv[3] = f2bf(accl[3]);
        *(s16x4*)((short*)hl + ((size_t)sl * N + node) * 32 + c) = hv;
        *(f32x4*)(hrs + ((size_t)sl * N + node) * 24 + c) = accr;
    }
}

// ---------------------------------------------------------------------------
// K2: p3agg — unchanged from R10 (best measured config): grid = bucket x
// slice (6256 blocks), slice pinned to XCD pair; 2-quad interleaved gather;
// hrs slice-local; out write-only.
// ---------------------------------------------------------------------------
__global__ __launch_bounds__(256) void p3agg(
    const unsigned* __restrict__ ebuf, const int* __restrict__ bcnt,
    const __hip_bfloat16* __restrict__ hl, const float* __restrict__ hrs,
    const float* __restrict__ bl, float* __restrict__ out, int nbuk, int N)
{
    const int xcd = blockIdx.x & 7;
    const int s  = xcd >> 1;                     // slice 0..3 (XCD-pair pinned)
    const int bu = ((blockIdx.x >> 3) << 1) | (xcd & 1);
    if (bu >= nbuk) return;

    __shared__ int cl[BUKN];
    __shared__ unsigned short sl[BUKN * CAP];    // 2 KB
    __shared__ unsigned ovl[OVL_MAX];
    __shared__ int ovc;
    const int t = threadIdx.x;
    if (t < BUKN) cl[t] = 0;
    if (t == 0) ovc = 0;
    __syncthreads();

    // ---- phase A: counting-sort this bucket's edges into LDS lists ----
    const int n = min(bcnt[bu], CAPB);
    const unsigned* eb = ebuf + (size_t)bu * CAPB;
    for (int i = t; i < n; i += 256) {
        unsigned e = eb[i];
        int dl = e >> 16, sv = (int)(e & 0xFFFFu);
        int pos = atomicAdd(&cl[dl], 1);         // LDS atomic
        if (pos < CAP) {
            sl[dl * CAP + pos] = (unsigned short)sv;
        } else {
            int o = atomicAdd(&ovc, 1);
            if (o < OVL_MAX) ovl[o] = e;
        }
    }
    __syncthreads();

    // ---- phase B: slice s; wave wv handles quads 2wv (A) and 2wv+1 (B) ----
    const int wv = t >> 6, lane = t & 63;
    const int nn = lane >> 4;                    // node in quad
    const int e4 = (lane >> 2) & 3;              // edge-parallel
    const int r  = lane & 3;                     // 12-B quarter of 48-B row
    const unsigned short* hs = (const unsigned short*)hl + (size_t)s * N * 32;
    const float* hp = hrs + (size_t)s * N * 24;
    const int o = s * 24 + r * 6;
    const float b0 = bl[o],     b1 = bl[o + 1], b2 = bl[o + 2];
    const float b3 = bl[o + 3], b4 = bl[o + 4], b5 = bl[o + 5];
    const int novc = min(ovc, OVL_MAX);

    const int nqA = wv * 8;                      // quad A base node
    const int nqB = wv * 8 + 4;                  // quad B base node
    const int degA = cl[nqA + nn], degB = cl[nqB + nn];
    const int dcmA = min(degA, CAP), dcmB = min(degB, CAP);
    int umA = max(max(cl[nqA], cl[nqA + 1]), max(cl[nqA + 2], cl[nqA + 3]));
    int umB = max(max(cl[nqB], cl[nqB + 1]), max(cl[nqB + 2], cl[nqB + 3]));
    int um = min(max(umA, umB), CAP);

    float a0 = 0.f, a1 = 0.f, a2 = 0.f, a3 = 0.f, a4 = 0.f, a5 = 0.f;
    float c0 = 0.f, c1 = 0.f, c2 = 0.f, c3 = 0.f, c4 = 0.f, c5 = 0.f;
    #pragma unroll 2
    for (int j = 0; j < um; j += 4) {
        int idx = j + e4;
        bool actA = idx < dcmA, actB = idx < dcmB;
        int nbA = actA ? (int)sl[(nqA + nn) * CAP + idx] : 0;
        int nbB = actB ? (int)sl[(nqB + nn) * CAP + idx] : 0;
        u32x3 pA = *(const u32x3*)((const char*)hs + (size_t)nbA * 64 + r * 12);
        u32x3 pB = *(const u32x3*)((const char*)hs + (size_t)nbB * 64 + r * 12);
        float mA = actA ? 1.f : 0.f, mB = actB ? 1.f : 0.f;
        a0 += mA * bf_lo(pA.x); a1 += mA * bf_hi(pA.x);
        a2 += mA * bf_lo(pA.y); a3 += mA * bf_hi(pA.y);
        a4 += mA * bf_lo(pA.z); a5 += mA * bf_hi(pA.z);
        c0 += mB * bf_lo(pB.x); c1 += mB * bf_hi(pB.x);
        c2 += mB * bf_lo(pB.y); c3 += mB * bf_hi(pB.y);
        c4 += mB * bf_lo(pB.z); c5 += mB * bf_hi(pB.z);
    }
    #pragma unroll
    for (int off = 4; off <= 8; off <<= 1) {
        a0 += __shfl_xor(a0, off); c0 += __shfl_xor(c0, off);
        a1 += __shfl_xor(a1, off); c1 += __shfl_xor(c1, off);
        a2 += __shfl_xor(a2, off); c2 += __shfl_xor(c2, off);
        a3 += __shfl_xor(a3, off); c3 += __shfl_xor(c3, off);
        a4 += __shfl_xor(a4, off); c4 += __shfl_xor(c4, off);
        a5 += __shfl_xor(a5, off); c5 += __shfl_xor(c5, off);
    }
    if (e4 == 0) {                               // 16 lanes: 4 nodes x 4 quarters
        #pragma unroll
        for (int half = 0; half < 2; ++half) {
            const int nq = half ? nqB : nqA;
            const int deg = half ? degB : degA;
            float v0 = half ? c0 : a0, v1 = half ? c1 : a1, v2 = half ? c2 : a2;
            float v3 = half ? c3 : a3, v4 = half ? c4 : a4, v5 = half ? c5 : a5;
            const int node = (bu << BUKSHIFT) + nq + nn;
            if (node < N) {
                for (int k = 0; k < novc; ++k) { // deg>32 tail (LDS, ~0-5)
                    unsigned e = ovl[k];
                    if ((int)(e >> 16) == nq + nn) {
                        int nb = (int)(e & 0xFFFFu);
                        u32x3 p = *(const u32x3*)((const char*)hs + (size_t)nb * 64 + r * 12);
                        v0 += bf_lo(p.x); v1 += bf_hi(p.x);
                        v2 += bf_lo(p.y); v3 += bf_hi(p.y);
                        v4 += bf_lo(p.z); v5 += bf_hi(p.z);
                    }
                }
                const float inv = 1.0f / fmaxf((float)deg, 1.0f);
                const float* rp = hp + (size_t)node * 24 + r * 6;
                float2 h0 = *(const float2*)rp;
                float2 h1 = *(const float2*)(rp + 2);
                float2 h2 = *(const float2*)(rp + 4);
                float* op = out + (size_t)node * D + o;
                float2 u0, u1, u2;
                u0.x = fmaxf(v0 * inv + b0 + h0.x, 0.f);
                u0.y = fmaxf(v1 * inv + b1 + h0.y, 0.f);
                u1.x = fmaxf(v2 * inv + b2 + h1.x, 0.f);
                u1.y = fmaxf(v3 * inv + b3 + h1.y, 0.f);
                u2.x = fmaxf(v4 * inv + b4 + h2.x, 0.f);
                u2.y = fmaxf(v5 * inv + b5 + h2.y, 0.f);
                *(float2*)op       = u0;
                *(float2*)(op + 2) = u1;
                *(float2*)(op + 4) = u2;
            }
        }
    }
}

extern "C" void kernel_launch(void* const* d_in, const int* in_sizes, int n_in,
                              void* d_out, int out_size, void* d_ws, size_t ws_size,
                              hipStream_t stream)
{
    const float* x  = (const float*)d_in[0];
    const int*   ei = (const int*)d_in[1];   // [2, E]: src row then dst row
    const float* Wl = (const float*)d_in[2];
    const float* bl = (const float*)d_in[3];
    const float* Wr = (const float*)d_in[4];
    float* out = (float*)d_out;

    const int N = in_sizes[0] / D;   // 50000
    const int E = in_sizes[1] / 2;   // 800000
    const int* src = ei;
    const int* dst = ei + E;
    const int nbuk = (N + BUKN - 1) >> BUKSHIFT; // 1563

    // ws layout (256-B aligned):
    //   wbf   36,864 B             frag-ordered bf16 W
    //   hl    4*N*32*2 = 12.8 MB   (64-B slice rows, bf16)
    //   hrs   4*N*24*4 = 19.2 MB   (slice-major root term, f32)
    //   bcnt  nbuk*4
    //   ebuf  nbuk*CAPB*4 = 6.4 MB
    char* p = (char*)d_ws;
    __hip_bfloat16* wbf = (__hip_bfloat16*)p;    p += 36864;
    __hip_bfloat16* hl  = (__hip_bfloat16*)p;    p += (size_t)4 * N * 32 * 2;
    float* hrs = (float*)p;                      p += (size_t)4 * N * 24 * 4;
    int* bcnt = (int*)p;                         p += ((size_t)nbuk * 4 + 255) / 256 * 256;
    unsigned* ebuf = (unsigned*)p;

    // K0: wbf build + bcnt zero (9 blocks)
    init_kernel<<<9, 256, 0, stream>>>(Wl, Wr, wbf, bcnt, nbuk);

    // K1: 512 LDS-staged scatter blocks + 782 gemm blocks
    const int nrt = N / 16;                      // 3125
    const int gemmb = (nrt + 3) / 4;             // 782
    p2_gemm<<<NB1 + gemmb, 256, 0, stream>>>(
        src, dst, bcnt, ebuf, x, wbf, hl, hrs, nbuk, N, E);

    // K2: bucket x slice grid, slice pinned to XCD pair
    const int aggb = ((nbuk + 1) / 2) * 8;       // 6256
    p3agg<<<aggb, 256, 0, stream>>>(ebuf, bcnt, hl, hrs, bl, out, nbuk, N);
}

// Round 13
// 129.249 us; speedup vs baseline: 1.0471x; 1.0471x over previous
//
#include <hip/hip_runtime.h>
#include <hip/hip_bf16.h>

#define D 96
#define CAP 32          // per-node neighbor capacity; deg>32 -> LDS overflow list
#define NB1 256         // scatter blocks (E/256 = 3125 edges each)
#define BUKSHIFT 5      // bucket = dst >> 5 : 32 nodes per bucket
#define BUKN 32
#define CAPB 1024       // bucket edge capacity (mean ~512, sigma ~23 -> +22 sigma)
#define NBUK_MAX 2048
#define KMAX 7          // ceil(nbuk/256): nbuk=1563 -> 7 strides of 256
#define OVL_MAX 256     // per-bucket LDS overflow (expected total ~2-5 edges)
#define CSMAX 3136      // staged-edge LDS capacity (CS = 3125)

typedef __attribute__((ext_vector_type(8))) short bf16x8;
typedef __attribute__((ext_vector_type(4))) float f32x4;
typedef unsigned u32x3 __attribute__((ext_vector_type(3), aligned(4)));

__device__ __forceinline__ short f2bf(float f)
{
    union { __hip_bfloat16 h; short s; } u;
    u.h = __float2bfloat16(f);
    return u.s;
}

__device__ __forceinline__ bf16x8 load_frag(const float* p)
{
    float4 lo = *(const float4*)p;
    float4 hi = *(const float4*)(p + 4);
    bf16x8 r;
    r[0] = f2bf(lo.x); r[1] = f2bf(lo.y); r[2] = f2bf(lo.z); r[3] = f2bf(lo.w);
    r[4] = f2bf(hi.x); r[5] = f2bf(hi.y); r[6] = f2bf(hi.z); r[7] = f2bf(hi.w);
    return r;
}

__device__ __forceinline__ float bf_lo(unsigned p) { return __uint_as_float(p << 16); }
__device__ __forceinline__ float bf_hi(unsigned p) { return __uint_as_float(p & 0xFFFF0000u); }

// ---------------------------------------------------------------------------
// K0: init — fragment-ordered bf16 W table wbf[36][64] (36 KB) + zero bcnt.
// ---------------------------------------------------------------------------
__global__ __launch_bounds__(256) void init_kernel(
    const float* __restrict__ Wl, const float* __restrict__ Wr,
    __hip_bfloat16* __restrict__ wbf, int* __restrict__ bcnt, int nbuk)
{
    const int idx = blockIdx.x * 256 + threadIdx.x;
    if (idx < nbuk) bcnt[idx] = 0;
    if (idx < 2304) {
        int mat = idx / 1152;                    // 0=Wl, 1=Wr
        int rem = idx - mat * 1152;
        int n  = rem / 12;                       // W row = output col (0..95)
        int k8 = rem - n * 12;                   // 8-float group along K
        const float* Wp = mat ? Wr : Wl;
        bf16x8 v = load_frag(Wp + (size_t)n * D + k8 * 8);
        int ct = n >> 4, m = n & 15, kt = k8 >> 2, quad = k8 & 3;
        ((bf16x8*)wbf)[(mat * 18 + ct * 3 + kt) * 64 + quad * 16 + m] = v;
    }
}

// ---------------------------------------------------------------------------
// K1 (fused): bid<NB1 -> LDS-staged self-reserving scatter (R20 config —
// best measured, 128.2us). NB1=256 keeps pass-2 at 400k aggregated atomics
// (R22's NB1=512 doubled it to 1/edge and regressed +7us). bid>=NB1 -> gemm
// role, NON-swapped MFMA (verified R4 layout; R22's swapped variant is
// unattributed in a regressed bundle — not re-risked).
// ---------------------------------------------------------------------------
__global__ __launch_bounds__(256) void p2_gemm(
    const int* __restrict__ src, const int* __restrict__ dst,
    int* __restrict__ bcnt, unsigned* __restrict__ ebuf,
    const float* __restrict__ x, const __hip_bfloat16* __restrict__ wbf,
    __hip_bfloat16* __restrict__ hl, float* __restrict__ hrs,
    int nbuk, int N, int E)
{
    if (blockIdx.x < NB1) {
        __shared__ int mo[NBUK_MAX];             // 8 KB
        __shared__ unsigned stg[CSMAX];          // 12.5 KB staged packed edges
        const int t = threadIdx.x;
        for (int i = t; i < nbuk; i += 256) mo[i] = 0;
        __syncthreads();
        const int CS = (E + NB1 - 1) / NB1;      // 3125
        const int base = blockIdx.x * CS;
        int lim = E - base; if (lim > CS) lim = CS; if (lim < 0) lim = 0;
        // pass 1: count + stage (dst/src loads pipelined by unroll)
        #pragma unroll 4
        for (int i = t; i < lim; i += 256) {
            int e = base + i;
            int d = dst[e], s = src[e];
            int bu = d >> BUKSHIFT;
            atomicAdd(&mo[bu], 1);
            stg[i] = (unsigned)s | ((unsigned)(d & (BUKN - 1)) << 16)
                                 | ((unsigned)bu << 21);
        }
        __syncthreads();
        // pass 2: aggregated global reservation, back-to-back atomics
        int c7[KMAX], b7[KMAX];
        #pragma unroll
        for (int k = 0; k < KMAX; ++k) {
            int i = t + k * 256;
            c7[k] = (i < nbuk) ? mo[i] : 0;
        }
        #pragma unroll
        for (int k = 0; k < KMAX; ++k) {
            int i = t + k * 256;
            b7[k] = (i < nbuk) ? atomicAdd(&bcnt[i], c7[k]) : 0;
        }
        #pragma unroll
        for (int k = 0; k < KMAX; ++k) {
            int i = t + k * 256;
            if (i < nbuk) mo[i] = i * CAPB + b7[k];
        }
        __syncthreads();
        // pass 3: place edges — no global reads, stores fire-and-forget
        #pragma unroll 4
        for (int i = t; i < lim; i += 256) {
            unsigned u = stg[i];
            int bu = (int)(u >> 21);
            int g = atomicAdd(&mo[bu], 1);       // LDS atomic
            if (g < (bu + 1) * CAPB)             // capacity guard (astronomic)
                ebuf[g] = u & 0x1FFFFFu;         // src | dl<<16
        }
        return;
    }

    // ---- gemm role ----
    const int gk = blockIdx.x - NB1;
    const int gwave = (gk * 256 + threadIdx.x) >> 6;
    const int nrt = N / 16;                      // 3125 (exact)
    if (gwave >= nrt) return;
    const int lane = threadIdx.x & 63;
    const int m = lane & 15, quad = lane >> 4;
    const int row = gwave * 16 + m;
    const bf16x8* wb = (const bf16x8*)wbf;

    bf16x8 a[3];
    #pragma unroll
    for (int kt = 0; kt < 3; ++kt)
        a[kt] = load_frag(x + (size_t)row * D + kt * 32 + quad * 8);

    const int orow = gwave * 16 + quad * 4;
    #pragma unroll
    for (int ct = 0; ct < 6; ++ct) {
        f32x4 accl = {0.f, 0.f, 0.f, 0.f};
        f32x4 accr = {0.f, 0.f, 0.f, 0.f};
        #pragma unroll
        for (int kt = 0; kt < 3; ++kt)
            accl = __builtin_amdgcn_mfma_f32_16x16x32_bf16(
                a[kt], wb[(ct * 3 + kt) * 64 + lane], accl, 0, 0, 0);
        #pragma unroll
        for (int kt = 0; kt < 3; ++kt)
            accr = __builtin_amdgcn_mfma_f32_16x16x32_bf16(
                a[kt], wb[(18 + ct * 3 + kt) * 64 + lane], accr, 0, 0, 0);
        int col = ct * 16 + m;
        int sl = col / 24, c = col - sl * 24;    // slice, col-in-slice
        #pragma unroll
        for (int r = 0; r < 4; ++r) {
            int node = orow + r;
            hl[((size_t)sl * N + node) * 32 + c] = __float2bfloat16(accl[r]);
            hrs[((size_t)sl * N + node) * 24 + c] = accr[r];   // slice-major
        }
    }
}

// ---------------------------------------------------------------------------
// K2: p3agg — R19/R10 config (best measured): grid = bucket x slice (6256
// blocks), slice pinned to XCD pair; phase B two-quad interleave; hrs
// slice-local; out write-only.
// ---------------------------------------------------------------------------
__global__ __launch_bounds__(256) void p3agg(
    const unsigned* __restrict__ ebuf, const int* __restrict__ bcnt,
    const __hip_bfloat16* __restrict__ hl, const float* __restrict__ hrs,
    const float* __restrict__ bl, float* __restrict__ out, int nbuk, int N)
{
    const int xcd = blockIdx.x & 7;
    const int s  = xcd >> 1;                     // slice 0..3 (XCD-pair pinned)
    const int bu = ((blockIdx.x >> 3) << 1) | (xcd & 1);
    if (bu >= nbuk) return;

    __shared__ int cl[BUKN];
    __shared__ unsigned short sl[BUKN * CAP];    // 2 KB
    __shared__ unsigned ovl[OVL_MAX];
    __shared__ int ovc;
    const int t = threadIdx.x;
    if (t < BUKN) cl[t] = 0;
    if (t == 0) ovc = 0;
    __syncthreads();

    // ---- phase A: counting-sort this bucket's edges into LDS lists ----
    const int n = min(bcnt[bu], CAPB);
    const unsigned* eb = ebuf + (size_t)bu * CAPB;
    for (int i = t; i < n; i += 256) {
        unsigned e = eb[i];
        int dl = e >> 16, sv = (int)(e & 0xFFFFu);
        int pos = atomicAdd(&cl[dl], 1);         // LDS atomic
        if (pos < CAP) {
            sl[dl * CAP + pos] = (unsigned short)sv;
        } else {
            int o = atomicAdd(&ovc, 1);
            if (o < OVL_MAX) ovl[o] = e;
        }
    }
    __syncthreads();

    // ---- phase B: slice s; wave wv handles quads 2wv (A) and 2wv+1 (B) ----
    const int wv = t >> 6, lane = t & 63;
    const int nn = lane >> 4;                    // node in quad
    const int e4 = (lane >> 2) & 3;              // edge-parallel
    const int r  = lane & 3;                     // 12-B quarter of 48-B row
    const unsigned short* hs = (const unsigned short*)hl + (size_t)s * N * 32;
    const float* hp = hrs + (size_t)s * N * 24;
    const int o = s * 24 + r * 6;
    const float b0 = bl[o],     b1 = bl[o + 1], b2 = bl[o + 2];
    const float b3 = bl[o + 3], b4 = bl[o + 4], b5 = bl[o + 5];
    const int novc = min(ovc, OVL_MAX);

    const int nqA = wv * 8;                      // quad A base node
    const int nqB = wv * 8 + 4;                  // quad B base node
    const int degA = cl[nqA + nn], degB = cl[nqB + nn];
    const int dcmA = min(degA, CAP), dcmB = min(degB, CAP);
    int umA = max(max(cl[nqA], cl[nqA + 1]), max(cl[nqA + 2], cl[nqA + 3]));
    int umB = max(max(cl[nqB], cl[nqB + 1]), max(cl[nqB + 2], cl[nqB + 3]));
    int um = min(max(umA, umB), CAP);

    float a0 = 0.f, a1 = 0.f, a2 = 0.f, a3 = 0.f, a4 = 0.f, a5 = 0.f;
    float c0 = 0.f, c1 = 0.f, c2 = 0.f, c3 = 0.f, c4 = 0.f, c5 = 0.f;
    #pragma unroll 2
    for (int j = 0; j < um; j += 4) {
        int idx = j + e4;
        bool actA = idx < dcmA, actB = idx < dcmB;
        int nbA = actA ? (int)sl[(nqA + nn) * CAP + idx] : 0;
        int nbB = actB ? (int)sl[(nqB + nn) * CAP + idx] : 0;
        u32x3 pA = *(const u32x3*)((const char*)hs + (size_t)nbA * 64 + r * 12);
        u32x3 pB = *(const u32x3*)((const char*)hs + (size_t)nbB * 64 + r * 12);
        float mA = actA ? 1.f : 0.f, mB = actB ? 1.f : 0.f;
        a0 += mA * bf_lo(pA.x); a1 += mA * bf_hi(pA.x);
        a2 += mA * bf_lo(pA.y); a3 += mA * bf_hi(pA.y);
        a4 += mA * bf_lo(pA.z); a5 += mA * bf_hi(pA.z);
        c0 += mB * bf_lo(pB.x); c1 += mB * bf_hi(pB.x);
        c2 += mB * bf_lo(pB.y); c3 += mB * bf_hi(pB.y);
        c4 += mB * bf_lo(pB.z); c5 += mB * bf_hi(pB.z);
    }
    #pragma unroll
    for (int off = 4; off <= 8; off <<= 1) {
        a0 += __shfl_xor(a0, off); c0 += __shfl_xor(c0, off);
        a1 += __shfl_xor(a1, off); c1 += __shfl_xor(c1, off);
        a2 += __shfl_xor(a2, off); c2 += __shfl_xor(c2, off);
        a3 += __shfl_xor(a3, off); c3 += __shfl_xor(c3, off);
        a4 += __shfl_xor(a4, off); c4 += __shfl_xor(c4, off);
        a5 += __shfl_xor(a5, off); c5 += __shfl_xor(c5, off);
    }
    if (e4 == 0) {                               // 16 lanes: 4 nodes x 4 quarters
        #pragma unroll
        for (int half = 0; half < 2; ++half) {
            const int nq = half ? nqB : nqA;
            const int deg = half ? degB : degA;
            float v0 = half ? c0 : a0, v1 = half ? c1 : a1, v2 = half ? c2 : a2;
            float v3 = half ? c3 : a3, v4 = half ? c4 : a4, v5 = half ? c5 : a5;
            const int node = (bu << BUKSHIFT) + nq + nn;
            if (node < N) {
                for (int k = 0; k < novc; ++k) { // deg>32 tail (LDS, ~0-5)
                    unsigned e = ovl[k];
                    if ((int)(e >> 16) == nq + nn) {
                        int nb = (int)(e & 0xFFFFu);
                        u32x3 p = *(const u32x3*)((const char*)hs + (size_t)nb * 64 + r * 12);
                        v0 += bf_lo(p.x); v1 += bf_hi(p.x);
                        v2 += bf_lo(p.y); v3 += bf_hi(p.y);
                        v4 += bf_lo(p.z); v5 += bf_hi(p.z);
                    }
                }
                const float inv = 1.0f / fmaxf((float)deg, 1.0f);
                const float* rp = hp + (size_t)node * 24 + r * 6;
                float2 h0 = *(const float2*)rp;
                float2 h1 = *(const float2*)(rp + 2);
                float2 h2 = *(const float2*)(rp + 4);
                float* op = out + (size_t)node * D + o;
                float2 u0, u1, u2;
                u0.x = fmaxf(v0 * inv + b0 + h0.x, 0.f);
                u0.y = fmaxf(v1 * inv + b1 + h0.y, 0.f);
                u1.x = fmaxf(v2 * inv + b2 + h1.x, 0.f);
                u1.y = fmaxf(v3 * inv + b3 + h1.y, 0.f);
                u2.x = fmaxf(v4 * inv + b4 + h2.x, 0.f);
                u2.y = fmaxf(v5 * inv + b5 + h2.y, 0.f);
                *(float2*)op       = u0;
                *(float2*)(op + 2) = u1;
                *(float2*)(op + 4) = u2;
            }
        }
    }
}

extern "C" void kernel_launch(void* const* d_in, const int* in_sizes, int n_in,
                              void* d_out, int out_size, void* d_ws, size_t ws_size,
                              hipStream_t stream)
{
    const float* x  = (const float*)d_in[0];
    const int*   ei = (const int*)d_in[1];   // [2, E]: src row then dst row
    const float* Wl = (const float*)d_in[2];
    const float* bl = (const float*)d_in[3];
    const float* Wr = (const float*)d_in[4];
    float* out = (float*)d_out;

    const int N = in_sizes[0] / D;   // 50000
    const int E = in_sizes[1] / 2;   // 800000
    const int* src = ei;
    const int* dst = ei + E;
    const int nbuk = (N + BUKN - 1) >> BUKSHIFT; // 1563

    // ws layout (256-B aligned):
    //   wbf   36,864 B             frag-ordered bf16 W
    //   hl    4*N*32*2 = 12.8 MB   (64-B slice rows, bf16)
    //   hrs   4*N*24*4 = 19.2 MB   (slice-major root term, f32)
    //   bcnt  nbuk*4
    //   ebuf  nbuk*CAPB*4 = 6.4 MB
    char* p = (char*)d_ws;
    __hip_bfloat16* wbf = (__hip_bfloat16*)p;    p += 36864;
    __hip_bfloat16* hl  = (__hip_bfloat16*)p;    p += (size_t)4 * N * 32 * 2;
    float* hrs = (float*)p;                      p += (size_t)4 * N * 24 * 4;
    int* bcnt = (int*)p;                         p += ((size_t)nbuk * 4 + 255) / 256 * 256;
    unsigned* ebuf = (unsigned*)p;

    // K0: wbf build + bcnt zero (9 blocks)
    init_kernel<<<9, 256, 0, stream>>>(Wl, Wr, wbf, bcnt, nbuk);

    // K1: 256 LDS-staged scatter blocks + 782 gemm blocks
    const int nrt = N / 16;                      // 3125
    const int gemmb = (nrt + 3) / 4;             // 782
    p2_gemm<<<NB1 + gemmb, 256, 0, stream>>>(
        src, dst, bcnt, ebuf, x, wbf, hl, hrs, nbuk, N, E);

    // K2: bucket x slice grid, slice pinned to XCD pair
    const int aggb = ((nbuk + 1) / 2) * 8;       // 6256
    p3agg<<<aggb, 256, 0, stream>>>(ebuf, bcnt, hl, hrs, bl, out, nbuk, N);
}